// Round 18
// baseline (393.839 us; speedup 1.0000x reference)
//
#include <hip/hip_runtime.h>

namespace {
constexpr int kB = 512;
constexpr int kT = 200;
constexpr int kI = 784;
constexpr int kH = 128;
constexpr int kO = 10;
constexpr int kM = kB * kT;  // 102400 rows
constexpr float kBeta = 0.9f;
constexpr float kThr = 1.0f;
}  // namespace

// ---------------------------------------------------------------------------
// Transpose W[N][K] -> WT[K][N]. 16x16 LDS tile. Proven r10-r17.
// ---------------------------------------------------------------------------
__global__ __launch_bounds__(256) void transposeW(const float* __restrict__ W,
                                                  float* __restrict__ WT,
                                                  int N, int K) {
  __shared__ float t[16][17];
  const int k0 = blockIdx.x * 16, n0 = blockIdx.y * 16;
  const int tx = threadIdx.x & 15, ty = threadIdx.x >> 4;
  t[ty][tx] = W[(size_t)(n0 + ty) * K + k0 + tx];
  __syncthreads();
  WT[(size_t)(k0 + ty) * N + n0 + tx] = t[tx][ty];
}

// ---------------------------------------------------------------------------
// GEMM1: cur1[M][128] = x[M][784] . W1T[784][128] + b1.  FULL K (no split):
// grid = 1600 blocks (6.25/CU) >= the ~5.5-block/CU residency ceiling
// measured r7-r16, so the split's extra queue depth gains ~0 while its
// partial write+read traffic (105 MB) and combine pass cost ~12-15us.
// Body = r12/r17's proven 64x128 / 128-thr / 8x8 kernel; bias in epilogue
// (r1-r6 proven-bitwise full-K ascending order).
// ---------------------------------------------------------------------------
__global__ __launch_bounds__(128, 4) void gemm64f(
    const float* __restrict__ A, const float* __restrict__ BT,
    const float* __restrict__ bias, float* __restrict__ C) {
  constexpr int BM = 64, BK = 16, KS = kI;
  constexpr int NSTEPS = KS / BK;  // 49
  __shared__ float As[BK][68];
  __shared__ float Bs[BK][132];
  const int tid = threadIdx.x;
  const int tx = tid & 15;
  const int ty = tid >> 4;
  const int row0 = blockIdx.x * BM;

  const int ar0 = tid >> 2;        // 0..31
  const int ar1 = ar0 + 32;
  const int ac4 = (tid & 3) * 4;
  const int sbk = tid >> 5;        // 0..3
  const int sbn4 = (tid & 31) * 4; // 0..124

  const float* aptr = A + (size_t)(row0 + ar0) * KS + ac4;
  const float* btptr = BT + (size_t)sbk * 128 + sbn4;

  float acc[8][8];
#pragma unroll
  for (int i = 0; i < 8; ++i)
#pragma unroll
    for (int j = 0; j < 8; ++j) acc[i][j] = 0.0f;

  for (int s = 0; s < NSTEPS; ++s) {
    const int k0 = s * BK;
    __syncthreads();
    {
      const float4 va0 = *reinterpret_cast<const float4*>(aptr + k0);
      const float4 va1 =
          *reinterpret_cast<const float4*>(aptr + (size_t)32 * KS + k0);
      As[ac4 + 0][ar0] = va0.x; As[ac4 + 1][ar0] = va0.y;
      As[ac4 + 2][ar0] = va0.z; As[ac4 + 3][ar0] = va0.w;
      As[ac4 + 0][ar1] = va1.x; As[ac4 + 1][ar1] = va1.y;
      As[ac4 + 2][ar1] = va1.z; As[ac4 + 3][ar1] = va1.w;
#pragma unroll
      for (int l = 0; l < 4; ++l) {
        const float4 vb = *reinterpret_cast<const float4*>(
            btptr + (size_t)(k0 + l * 4) * 128);
        *reinterpret_cast<float4*>(&Bs[sbk + l * 4][sbn4]) = vb;
      }
    }
    __syncthreads();
#pragma unroll
    for (int kk = 0; kk < BK; ++kk) {
      float a[8], b[8];
      *reinterpret_cast<float4*>(&a[0]) =
          *reinterpret_cast<const float4*>(&As[kk][ty * 4]);
      *reinterpret_cast<float4*>(&a[4]) =
          *reinterpret_cast<const float4*>(&As[kk][32 + ty * 4]);
      *reinterpret_cast<float4*>(&b[0]) =
          *reinterpret_cast<const float4*>(&Bs[kk][tx * 4]);
      *reinterpret_cast<float4*>(&b[4]) =
          *reinterpret_cast<const float4*>(&Bs[kk][64 + tx * 4]);
#pragma unroll
      for (int i = 0; i < 8; ++i)
#pragma unroll
        for (int j = 0; j < 8; ++j) acc[i][j] = fmaf(a[i], b[j], acc[i][j]);
    }
  }

#pragma unroll
  for (int i = 0; i < 8; ++i) {
    const int m = (i < 4) ? (ty * 4 + i) : (32 + ty * 4 + (i - 4));
    const size_t r = (size_t)(row0 + m);
#pragma unroll
    for (int jh = 0; jh < 2; ++jh) {
      const int n = jh * 64 + tx * 4;
      float4 v;
      v.x = acc[i][jh * 4 + 0] + bias[n + 0];
      v.y = acc[i][jh * 4 + 1] + bias[n + 1];
      v.z = acc[i][jh * 4 + 2] + bias[n + 2];
      v.w = acc[i][jh * 4 + 3] + bias[n + 3];
      *reinterpret_cast<float4*>(&C[r * 128 + n]) = v;
    }
  }
}

// ---------------------------------------------------------------------------
// GEMM2: cur2[M][128] = s1_u8[M][128] . W2T[128][128] + b2. (r17 verbatim)
// float(u8 in {0,1}) exact -> bitwise-identical to fp32 path.
// ---------------------------------------------------------------------------
__global__ __launch_bounds__(128, 4) void gemm64u8(
    const unsigned char* __restrict__ A, const float* __restrict__ BT,
    const float* __restrict__ bias, float* __restrict__ C) {
  constexpr int BM = 64, BK = 16, KS = kH;
  __shared__ float As[BK][68];
  __shared__ float Bs[BK][132];
  const int tid = threadIdx.x;
  const int tx = tid & 15;
  const int ty = tid >> 4;
  const int row0 = blockIdx.x * BM;

  const int ar0 = tid >> 2;
  const int ar1 = ar0 + 32;
  const int ac4 = (tid & 3) * 4;
  const int sbk = tid >> 5;
  const int sbn4 = (tid & 31) * 4;

  const unsigned char* aptr = A + (size_t)(row0 + ar0) * KS + ac4;
  const float* btptr = BT + (size_t)sbk * 128 + sbn4;

  float acc[8][8];
#pragma unroll
  for (int i = 0; i < 8; ++i)
#pragma unroll
    for (int j = 0; j < 8; ++j) acc[i][j] = 0.0f;

  for (int s = 0; s < KS / BK; ++s) {
    const int k0 = s * BK;
    __syncthreads();
    {
      const uchar4 ua0 = *reinterpret_cast<const uchar4*>(aptr + k0);
      const uchar4 ua1 =
          *reinterpret_cast<const uchar4*>(aptr + (size_t)32 * KS + k0);
      As[ac4 + 0][ar0] = (float)ua0.x; As[ac4 + 1][ar0] = (float)ua0.y;
      As[ac4 + 2][ar0] = (float)ua0.z; As[ac4 + 3][ar0] = (float)ua0.w;
      As[ac4 + 0][ar1] = (float)ua1.x; As[ac4 + 1][ar1] = (float)ua1.y;
      As[ac4 + 2][ar1] = (float)ua1.z; As[ac4 + 3][ar1] = (float)ua1.w;
#pragma unroll
      for (int l = 0; l < 4; ++l) {
        const float4 vb = *reinterpret_cast<const float4*>(
            btptr + (size_t)(k0 + l * 4) * 128);
        *reinterpret_cast<float4*>(&Bs[sbk + l * 4][sbn4]) = vb;
      }
    }
    __syncthreads();
#pragma unroll
    for (int kk = 0; kk < BK; ++kk) {
      float a[8], b[8];
      *reinterpret_cast<float4*>(&a[0]) =
          *reinterpret_cast<const float4*>(&As[kk][ty * 4]);
      *reinterpret_cast<float4*>(&a[4]) =
          *reinterpret_cast<const float4*>(&As[kk][32 + ty * 4]);
      *reinterpret_cast<float4*>(&b[0]) =
          *reinterpret_cast<const float4*>(&Bs[kk][tx * 4]);
      *reinterpret_cast<float4*>(&b[4]) =
          *reinterpret_cast<const float4*>(&Bs[kk][64 + tx * 4]);
#pragma unroll
      for (int i = 0; i < 8; ++i)
#pragma unroll
        for (int j = 0; j < 8; ++j) acc[i][j] = fmaf(a[i], b[j], acc[i][j]);
    }
  }

#pragma unroll
  for (int i = 0; i < 8; ++i) {
    const int m = (i < 4) ? (ty * 4 + i) : (32 + ty * 4 + (i - 4));
    const size_t r = (size_t)(row0 + m);
#pragma unroll
    for (int jh = 0; jh < 2; ++jh) {
      const int n = jh * 64 + tx * 4;
      float4 v;
      v.x = acc[i][jh * 4 + 0] + bias[n + 0];
      v.y = acc[i][jh * 4 + 1] + bias[n + 1];
      v.z = acc[i][jh * 4 + 2] + bias[n + 2];
      v.w = acc[i][jh * 4 + 3] + bias[n + 3];
      *reinterpret_cast<float4*>(&C[r * 128 + n]) = v;
    }
  }
}

#define LIF_STEP(mm, ss, curexpr)                                      \
  {                                                                    \
    const float cur_ = (curexpr);                                      \
    mm = __fsub_rn(__fadd_rn(__fmul_rn(kBeta, mm), cur_), ss);         \
    ss = (mm > kThr) ? 1.0f : 0.0f;                                    \
  }

// ---------------------------------------------------------------------------
// LIF scan over [B,T,128]: reads biased fp32 currents, writes u8 spikes.
// Used for layers 1 AND 2 (both GEMMs fuse their bias now). r17-proven
// float2 chains + depth-4 load pipeline.
// ---------------------------------------------------------------------------
__global__ __launch_bounds__(128) void lif_scan_u8(
    const float* __restrict__ buf, unsigned char* __restrict__ S) {
  const int g = blockIdx.x * 128 + threadIdx.x;  // 0..32767
  const int b = g >> 6;
  const int h2 = (g & 63) * 2;
  const size_t base = (size_t)b * kT * 128 + h2;
#define LD(t) (*reinterpret_cast<const float2*>(&buf[base + (size_t)(t)*128]))
  float2 cA = LD(0), cB = LD(1), cC = LD(2), cD = LD(3);
  float m0 = 0.f, m1 = 0.f, s0 = 0.f, s1 = 0.f;
  for (int t = 0; t < kT; t += 2) {
    const int pa = (t + 4 < kT) ? t + 4 : kT - 1;
    const int pb = (t + 5 < kT) ? t + 5 : kT - 1;
    const float2 nA = LD(pa), nB = LD(pb);
    LIF_STEP(m0, s0, cA.x);
    LIF_STEP(m1, s1, cA.y);
    *reinterpret_cast<uchar2*>(&S[base + (size_t)t * 128]) =
        make_uchar2((unsigned char)s0, (unsigned char)s1);
    LIF_STEP(m0, s0, cB.x);
    LIF_STEP(m1, s1, cB.y);
    *reinterpret_cast<uchar2*>(&S[base + (size_t)(t + 1) * 128]) =
        make_uchar2((unsigned char)s0, (unsigned char)s1);
    cA = cC; cB = cD; cC = nA; cD = nB;
  }
#undef LD
}

// ---------------------------------------------------------------------------
// GEMM3: cur3[M][10] = s2_u8[M][128] . W3[10][128]^T + b3. (r17 verbatim)
// ---------------------------------------------------------------------------
__global__ __launch_bounds__(320) void gemm3_u8(
    const unsigned char* __restrict__ A, const float* __restrict__ W3,
    const float* __restrict__ b3, float* __restrict__ C) {
  __shared__ float Ss[64][132];
  __shared__ float Ws[10][132];
  __shared__ float bs[10];
  const int tid = threadIdx.x;
  const size_t row0 = (size_t)blockIdx.x * 64;

  {
    const int r = tid >> 5;
    const int c4 = (tid & 31) * 4;
    const float4 v = *reinterpret_cast<const float4*>(&W3[r * 128 + c4]);
    Ws[r][c4 + 0] = v.x;
    Ws[r][c4 + 1] = v.y;
    Ws[r][c4 + 2] = v.z;
    Ws[r][c4 + 3] = v.w;
    if (tid < 10) bs[tid] = b3[tid];
  }
  for (int fi = tid; fi < 2048; fi += 320) {
    const int r = fi >> 5;
    const int c4 = (fi & 31) * 4;
    const uchar4 v =
        *reinterpret_cast<const uchar4*>(&A[(row0 + r) * 128 + c4]);
    Ss[r][c4 + 0] = (float)v.x;
    Ss[r][c4 + 1] = (float)v.y;
    Ss[r][c4 + 2] = (float)v.z;
    Ss[r][c4 + 3] = (float)v.w;
  }
  __syncthreads();

#pragma unroll
  for (int l = 0; l < 2; ++l) {
    const int idx = tid + l * 320;
    const int r = idx / 10;
    const int o = idx - r * 10;
    float acc = bs[o];
#pragma unroll
    for (int k = 0; k < 128; k += 4) {
      const float4 a = *reinterpret_cast<const float4*>(&Ss[r][k]);
      const float4 w = *reinterpret_cast<const float4*>(&Ws[o][k]);
      acc = fmaf(a.x, w.x, acc);
      acc = fmaf(a.y, w.y, acc);
      acc = fmaf(a.z, w.z, acc);
      acc = fmaf(a.w, w.w, acc);
    }
    C[(row0 + r) * 10 + o] = acc;
  }
}

// ---------------------------------------------------------------------------
// Output LIF scan -> out[t][b][o]. (unchanged, proven)
// ---------------------------------------------------------------------------
__global__ __launch_bounds__(256) void lif_scan_out(
    const float* __restrict__ cur3, float* __restrict__ out) {
  const int g = blockIdx.x * 256 + threadIdx.x;  // 0..5119
  if (g >= kB * kO) return;
  const int b = g / kO;
  const int o = g - b * kO;
  float m = 0.0f, s = 0.0f;
#pragma unroll 4
  for (int t = 0; t < kT; ++t) {
    const float c = cur3[((size_t)b * kT + t) * kO + o];
    m = __fsub_rn(__fadd_rn(__fmul_rn(kBeta, m), c), s);
    s = (m > kThr) ? 1.0f : 0.0f;
    out[(size_t)t * (kB * kO) + g] = s;
  }
}

extern "C" void kernel_launch(void* const* d_in, const int* in_sizes, int n_in,
                              void* d_out, int out_size, void* d_ws,
                              size_t ws_size, hipStream_t stream) {
  (void)in_sizes;
  (void)n_in;
  (void)out_size;
  (void)ws_size;
  const float* x = (const float*)d_in[0];    // [B,T,784]
  const float* W1 = (const float*)d_in[1];   // [128,784]
  const float* b1 = (const float*)d_in[2];   // [128]
  const float* W2 = (const float*)d_in[3];   // [128,128]
  const float* b2 = (const float*)d_in[4];   // [128]
  const float* W3 = (const float*)d_in[5];   // [10,128]
  const float* b3 = (const float*)d_in[6];   // [10]
  float* out = (float*)d_out;                // [T,B,10] = 4.1 MB

  const size_t bufElems = (size_t)kM * kH;   // 13.1M elems
  float* P0 = (float*)d_ws;                  // cur1 -> cur3
  float* P1 = P0 + bufElems;                 // cur2
  unsigned char* S1 = (unsigned char*)(P1 + bufElems);  // s1 u8, 13.1 MB
  unsigned char* S2 = S1 + bufElems;                    // s2 u8, 13.1 MB

  // W1T + W2T (467 KB) stashed at head of d_out; overwritten by the final
  // lif_scan_out (proven r10-r17 pattern).
  float* W1T = out;
  float* W2T = W1T + (size_t)kI * kH;

  transposeW<<<dim3(kI / 16, kH / 16), 256, 0, stream>>>(W1, W1T, kH, kI);
  transposeW<<<dim3(kH / 16, kH / 16), 256, 0, stream>>>(W2, W2T, kH, kH);

  // Layer 1: full-K GEMM, bias fused; cur1 -> P0; scan -> S1 u8.
  gemm64f<<<kM / 64, 128, 0, stream>>>(x, W1T, b1, P0);
  lif_scan_u8<<<256, 128, 0, stream>>>(P0, S1);
  // Layer 2: full-K u8-A GEMM, bias fused; cur2 -> P1; scan -> S2 u8.
  gemm64u8<<<kM / 64, 128, 0, stream>>>(S1, W2T, b2, P1);
  lif_scan_u8<<<256, 128, 0, stream>>>(P1, S2);
  // Layer 3: cur3 -> P0; final scan -> out.
  gemm3_u8<<<kM / 64, 320, 0, stream>>>(S2, W3, b3, P0);
  lif_scan_out<<<(kB * kO + 255) / 256, 256, 0, stream>>>(P0, out);
}

// Round 19
// 393.705 us; speedup vs baseline: 1.0003x; 1.0003x over previous
//
#include <hip/hip_runtime.h>

namespace {
constexpr int kB = 512;
constexpr int kT = 200;
constexpr int kI = 784;
constexpr int kH = 128;
constexpr int kO = 10;
constexpr int kM = kB * kT;  // 102400 rows
constexpr float kBeta = 0.9f;
constexpr float kThr = 1.0f;
}  // namespace

// ---------------------------------------------------------------------------
// Transpose W[N][K] -> WT[K][N]. 16x16 LDS tile. Proven r10-r17.
// ---------------------------------------------------------------------------
__global__ __launch_bounds__(256) void transposeW(const float* __restrict__ W,
                                                  float* __restrict__ WT,
                                                  int N, int K) {
  __shared__ float t[16][17];
  const int k0 = blockIdx.x * 16, n0 = blockIdx.y * 16;
  const int tx = threadIdx.x & 15, ty = threadIdx.x >> 4;
  t[ty][tx] = W[(size_t)(n0 + ty) * K + k0 + tx];
  __syncthreads();
  WT[(size_t)(k0 + ty) * N + n0 + tx] = t[tx][ty];
}

// ---------------------------------------------------------------------------
// GEMM1: cur1[M][128] = x[M][784] . W1T[784][128] + b1.  FULL K (no split):
// grid = 1600 blocks (6.25/CU) >= the ~5.5-block/CU residency ceiling
// measured r7-r16, so the split's extra queue depth gains ~0 while its
// partial write+read traffic (105 MB) and combine pass cost ~12-15us.
// Body = r12/r17's proven 64x128 / 128-thr / 8x8 kernel; bias in epilogue
// (r1-r6 proven-bitwise full-K ascending order).
// ---------------------------------------------------------------------------
__global__ __launch_bounds__(128, 4) void gemm64f(
    const float* __restrict__ A, const float* __restrict__ BT,
    const float* __restrict__ bias, float* __restrict__ C) {
  constexpr int BM = 64, BK = 16, KS = kI;
  constexpr int NSTEPS = KS / BK;  // 49
  __shared__ float As[BK][68];
  __shared__ float Bs[BK][132];
  const int tid = threadIdx.x;
  const int tx = tid & 15;
  const int ty = tid >> 4;
  const int row0 = blockIdx.x * BM;

  const int ar0 = tid >> 2;        // 0..31
  const int ar1 = ar0 + 32;
  const int ac4 = (tid & 3) * 4;
  const int sbk = tid >> 5;        // 0..3
  const int sbn4 = (tid & 31) * 4; // 0..124

  const float* aptr = A + (size_t)(row0 + ar0) * KS + ac4;
  const float* btptr = BT + (size_t)sbk * 128 + sbn4;

  float acc[8][8];
#pragma unroll
  for (int i = 0; i < 8; ++i)
#pragma unroll
    for (int j = 0; j < 8; ++j) acc[i][j] = 0.0f;

  for (int s = 0; s < NSTEPS; ++s) {
    const int k0 = s * BK;
    __syncthreads();
    {
      const float4 va0 = *reinterpret_cast<const float4*>(aptr + k0);
      const float4 va1 =
          *reinterpret_cast<const float4*>(aptr + (size_t)32 * KS + k0);
      As[ac4 + 0][ar0] = va0.x; As[ac4 + 1][ar0] = va0.y;
      As[ac4 + 2][ar0] = va0.z; As[ac4 + 3][ar0] = va0.w;
      As[ac4 + 0][ar1] = va1.x; As[ac4 + 1][ar1] = va1.y;
      As[ac4 + 2][ar1] = va1.z; As[ac4 + 3][ar1] = va1.w;
#pragma unroll
      for (int l = 0; l < 4; ++l) {
        const float4 vb = *reinterpret_cast<const float4*>(
            btptr + (size_t)(k0 + l * 4) * 128);
        *reinterpret_cast<float4*>(&Bs[sbk + l * 4][sbn4]) = vb;
      }
    }
    __syncthreads();
#pragma unroll
    for (int kk = 0; kk < BK; ++kk) {
      float a[8], b[8];
      *reinterpret_cast<float4*>(&a[0]) =
          *reinterpret_cast<const float4*>(&As[kk][ty * 4]);
      *reinterpret_cast<float4*>(&a[4]) =
          *reinterpret_cast<const float4*>(&As[kk][32 + ty * 4]);
      *reinterpret_cast<float4*>(&b[0]) =
          *reinterpret_cast<const float4*>(&Bs[kk][tx * 4]);
      *reinterpret_cast<float4*>(&b[4]) =
          *reinterpret_cast<const float4*>(&Bs[kk][64 + tx * 4]);
#pragma unroll
      for (int i = 0; i < 8; ++i)
#pragma unroll
        for (int j = 0; j < 8; ++j) acc[i][j] = fmaf(a[i], b[j], acc[i][j]);
    }
  }

#pragma unroll
  for (int i = 0; i < 8; ++i) {
    const int m = (i < 4) ? (ty * 4 + i) : (32 + ty * 4 + (i - 4));
    const size_t r = (size_t)(row0 + m);
#pragma unroll
    for (int jh = 0; jh < 2; ++jh) {
      const int n = jh * 64 + tx * 4;
      float4 v;
      v.x = acc[i][jh * 4 + 0] + bias[n + 0];
      v.y = acc[i][jh * 4 + 1] + bias[n + 1];
      v.z = acc[i][jh * 4 + 2] + bias[n + 2];
      v.w = acc[i][jh * 4 + 3] + bias[n + 3];
      *reinterpret_cast<float4*>(&C[r * 128 + n]) = v;
    }
  }
}

// ---------------------------------------------------------------------------
// GEMM2: cur2[M][128] = s1_u8[M][128] . W2T[128][128] + b2. (r17 verbatim)
// float(u8 in {0,1}) exact -> bitwise-identical to fp32 path.
// ---------------------------------------------------------------------------
__global__ __launch_bounds__(128, 4) void gemm64u8(
    const unsigned char* __restrict__ A, const float* __restrict__ BT,
    const float* __restrict__ bias, float* __restrict__ C) {
  constexpr int BM = 64, BK = 16, KS = kH;
  __shared__ float As[BK][68];
  __shared__ float Bs[BK][132];
  const int tid = threadIdx.x;
  const int tx = tid & 15;
  const int ty = tid >> 4;
  const int row0 = blockIdx.x * BM;

  const int ar0 = tid >> 2;
  const int ar1 = ar0 + 32;
  const int ac4 = (tid & 3) * 4;
  const int sbk = tid >> 5;
  const int sbn4 = (tid & 31) * 4;

  const unsigned char* aptr = A + (size_t)(row0 + ar0) * KS + ac4;
  const float* btptr = BT + (size_t)sbk * 128 + sbn4;

  float acc[8][8];
#pragma unroll
  for (int i = 0; i < 8; ++i)
#pragma unroll
    for (int j = 0; j < 8; ++j) acc[i][j] = 0.0f;

  for (int s = 0; s < KS / BK; ++s) {
    const int k0 = s * BK;
    __syncthreads();
    {
      const uchar4 ua0 = *reinterpret_cast<const uchar4*>(aptr + k0);
      const uchar4 ua1 =
          *reinterpret_cast<const uchar4*>(aptr + (size_t)32 * KS + k0);
      As[ac4 + 0][ar0] = (float)ua0.x; As[ac4 + 1][ar0] = (float)ua0.y;
      As[ac4 + 2][ar0] = (float)ua0.z; As[ac4 + 3][ar0] = (float)ua0.w;
      As[ac4 + 0][ar1] = (float)ua1.x; As[ac4 + 1][ar1] = (float)ua1.y;
      As[ac4 + 2][ar1] = (float)ua1.z; As[ac4 + 3][ar1] = (float)ua1.w;
#pragma unroll
      for (int l = 0; l < 4; ++l) {
        const float4 vb = *reinterpret_cast<const float4*>(
            btptr + (size_t)(k0 + l * 4) * 128);
        *reinterpret_cast<float4*>(&Bs[sbk + l * 4][sbn4]) = vb;
      }
    }
    __syncthreads();
#pragma unroll
    for (int kk = 0; kk < BK; ++kk) {
      float a[8], b[8];
      *reinterpret_cast<float4*>(&a[0]) =
          *reinterpret_cast<const float4*>(&As[kk][ty * 4]);
      *reinterpret_cast<float4*>(&a[4]) =
          *reinterpret_cast<const float4*>(&As[kk][32 + ty * 4]);
      *reinterpret_cast<float4*>(&b[0]) =
          *reinterpret_cast<const float4*>(&Bs[kk][tx * 4]);
      *reinterpret_cast<float4*>(&b[4]) =
          *reinterpret_cast<const float4*>(&Bs[kk][64 + tx * 4]);
#pragma unroll
      for (int i = 0; i < 8; ++i)
#pragma unroll
        for (int j = 0; j < 8; ++j) acc[i][j] = fmaf(a[i], b[j], acc[i][j]);
    }
  }

#pragma unroll
  for (int i = 0; i < 8; ++i) {
    const int m = (i < 4) ? (ty * 4 + i) : (32 + ty * 4 + (i - 4));
    const size_t r = (size_t)(row0 + m);
#pragma unroll
    for (int jh = 0; jh < 2; ++jh) {
      const int n = jh * 64 + tx * 4;
      float4 v;
      v.x = acc[i][jh * 4 + 0] + bias[n + 0];
      v.y = acc[i][jh * 4 + 1] + bias[n + 1];
      v.z = acc[i][jh * 4 + 2] + bias[n + 2];
      v.w = acc[i][jh * 4 + 3] + bias[n + 3];
      *reinterpret_cast<float4*>(&C[r * 128 + n]) = v;
    }
  }
}

#define LIF_STEP(mm, ss, curexpr)                                      \
  {                                                                    \
    const float cur_ = (curexpr);                                      \
    mm = __fsub_rn(__fadd_rn(__fmul_rn(kBeta, mm), cur_), ss);         \
    ss = (mm > kThr) ? 1.0f : 0.0f;                                    \
  }

// ---------------------------------------------------------------------------
// LIF scan over [B,T,128]: reads biased fp32 currents, writes u8 spikes.
// Used for layers 1 AND 2 (both GEMMs fuse their bias now). r17-proven
// float2 chains + depth-4 load pipeline.
// ---------------------------------------------------------------------------
__global__ __launch_bounds__(128) void lif_scan_u8(
    const float* __restrict__ buf, unsigned char* __restrict__ S) {
  const int g = blockIdx.x * 128 + threadIdx.x;  // 0..32767
  const int b = g >> 6;
  const int h2 = (g & 63) * 2;
  const size_t base = (size_t)b * kT * 128 + h2;
#define LD(t) (*reinterpret_cast<const float2*>(&buf[base + (size_t)(t)*128]))
  float2 cA = LD(0), cB = LD(1), cC = LD(2), cD = LD(3);
  float m0 = 0.f, m1 = 0.f, s0 = 0.f, s1 = 0.f;
  for (int t = 0; t < kT; t += 2) {
    const int pa = (t + 4 < kT) ? t + 4 : kT - 1;
    const int pb = (t + 5 < kT) ? t + 5 : kT - 1;
    const float2 nA = LD(pa), nB = LD(pb);
    LIF_STEP(m0, s0, cA.x);
    LIF_STEP(m1, s1, cA.y);
    *reinterpret_cast<uchar2*>(&S[base + (size_t)t * 128]) =
        make_uchar2((unsigned char)s0, (unsigned char)s1);
    LIF_STEP(m0, s0, cB.x);
    LIF_STEP(m1, s1, cB.y);
    *reinterpret_cast<uchar2*>(&S[base + (size_t)(t + 1) * 128]) =
        make_uchar2((unsigned char)s0, (unsigned char)s1);
    cA = cC; cB = cD; cC = nA; cD = nB;
  }
#undef LD
}

// ---------------------------------------------------------------------------
// GEMM3: cur3[M][10] = s2_u8[M][128] . W3[10][128]^T + b3. (r17 verbatim)
// ---------------------------------------------------------------------------
__global__ __launch_bounds__(320) void gemm3_u8(
    const unsigned char* __restrict__ A, const float* __restrict__ W3,
    const float* __restrict__ b3, float* __restrict__ C) {
  __shared__ float Ss[64][132];
  __shared__ float Ws[10][132];
  __shared__ float bs[10];
  const int tid = threadIdx.x;
  const size_t row0 = (size_t)blockIdx.x * 64;

  {
    const int r = tid >> 5;
    const int c4 = (tid & 31) * 4;
    const float4 v = *reinterpret_cast<const float4*>(&W3[r * 128 + c4]);
    Ws[r][c4 + 0] = v.x;
    Ws[r][c4 + 1] = v.y;
    Ws[r][c4 + 2] = v.z;
    Ws[r][c4 + 3] = v.w;
    if (tid < 10) bs[tid] = b3[tid];
  }
  for (int fi = tid; fi < 2048; fi += 320) {
    const int r = fi >> 5;
    const int c4 = (fi & 31) * 4;
    const uchar4 v =
        *reinterpret_cast<const uchar4*>(&A[(row0 + r) * 128 + c4]);
    Ss[r][c4 + 0] = (float)v.x;
    Ss[r][c4 + 1] = (float)v.y;
    Ss[r][c4 + 2] = (float)v.z;
    Ss[r][c4 + 3] = (float)v.w;
  }
  __syncthreads();

#pragma unroll
  for (int l = 0; l < 2; ++l) {
    const int idx = tid + l * 320;
    const int r = idx / 10;
    const int o = idx - r * 10;
    float acc = bs[o];
#pragma unroll
    for (int k = 0; k < 128; k += 4) {
      const float4 a = *reinterpret_cast<const float4*>(&Ss[r][k]);
      const float4 w = *reinterpret_cast<const float4*>(&Ws[o][k]);
      acc = fmaf(a.x, w.x, acc);
      acc = fmaf(a.y, w.y, acc);
      acc = fmaf(a.z, w.z, acc);
      acc = fmaf(a.w, w.w, acc);
    }
    C[(row0 + r) * 10 + o] = acc;
  }
}

// ---------------------------------------------------------------------------
// Output LIF scan -> out[t][b][o]. (unchanged, proven)
// ---------------------------------------------------------------------------
__global__ __launch_bounds__(256) void lif_scan_out(
    const float* __restrict__ cur3, float* __restrict__ out) {
  const int g = blockIdx.x * 256 + threadIdx.x;  // 0..5119
  if (g >= kB * kO) return;
  const int b = g / kO;
  const int o = g - b * kO;
  float m = 0.0f, s = 0.0f;
#pragma unroll 4
  for (int t = 0; t < kT; ++t) {
    const float c = cur3[((size_t)b * kT + t) * kO + o];
    m = __fsub_rn(__fadd_rn(__fmul_rn(kBeta, m), c), s);
    s = (m > kThr) ? 1.0f : 0.0f;
    out[(size_t)t * (kB * kO) + g] = s;
  }
}

extern "C" void kernel_launch(void* const* d_in, const int* in_sizes, int n_in,
                              void* d_out, int out_size, void* d_ws,
                              size_t ws_size, hipStream_t stream) {
  (void)in_sizes;
  (void)n_in;
  (void)out_size;
  (void)ws_size;
  const float* x = (const float*)d_in[0];    // [B,T,784]
  const float* W1 = (const float*)d_in[1];   // [128,784]
  const float* b1 = (const float*)d_in[2];   // [128]
  const float* W2 = (const float*)d_in[3];   // [128,128]
  const float* b2 = (const float*)d_in[4];   // [128]
  const float* W3 = (const float*)d_in[5];   // [10,128]
  const float* b3 = (const float*)d_in[6];   // [10]
  float* out = (float*)d_out;                // [T,B,10] = 4.1 MB

  const size_t bufElems = (size_t)kM * kH;   // 13.1M elems
  float* P0 = (float*)d_ws;                  // cur1 -> cur3
  float* P1 = P0 + bufElems;                 // cur2
  unsigned char* S1 = (unsigned char*)(P1 + bufElems);  // s1 u8, 13.1 MB
  unsigned char* S2 = S1 + bufElems;                    // s2 u8, 13.1 MB

  // W1T + W2T (467 KB) stashed at head of d_out; overwritten by the final
  // lif_scan_out (proven r10-r17 pattern).
  float* W1T = out;
  float* W2T = W1T + (size_t)kI * kH;

  transposeW<<<dim3(kI / 16, kH / 16), 256, 0, stream>>>(W1, W1T, kH, kI);
  transposeW<<<dim3(kH / 16, kH / 16), 256, 0, stream>>>(W2, W2T, kH, kH);

  // Layer 1: full-K GEMM, bias fused; cur1 -> P0; scan -> S1 u8.
  gemm64f<<<kM / 64, 128, 0, stream>>>(x, W1T, b1, P0);
  lif_scan_u8<<<256, 128, 0, stream>>>(P0, S1);
  // Layer 2: full-K u8-A GEMM, bias fused; cur2 -> P1; scan -> S2 u8.
  gemm64u8<<<kM / 64, 128, 0, stream>>>(S1, W2T, b2, P1);
  lif_scan_u8<<<256, 128, 0, stream>>>(P1, S2);
  // Layer 3: cur3 -> P0; final scan -> out.
  gemm3_u8<<<kM / 64, 320, 0, stream>>>(S2, W3, b3, P0);
  lif_scan_out<<<(kB * kO + 255) / 256, 256, 0, stream>>>(P0, out);
}

// Round 20
// 392.562 us; speedup vs baseline: 1.0033x; 1.0029x over previous
//
#include <hip/hip_runtime.h>

namespace {
constexpr int kB = 512;
constexpr int kT = 200;
constexpr int kI = 784;
constexpr int kH = 128;
constexpr int kO = 10;
constexpr int kM = kB * kT;  // 102400 rows
constexpr float kBeta = 0.9f;
constexpr float kThr = 1.0f;
}  // namespace

// ---------------------------------------------------------------------------
// Transpose W[N][K] -> WT[K][N]. 16x16 LDS tile. Proven r10-r17.
// ---------------------------------------------------------------------------
__global__ __launch_bounds__(256) void transposeW(const float* __restrict__ W,
                                                  float* __restrict__ WT,
                                                  int N, int K) {
  __shared__ float t[16][17];
  const int k0 = blockIdx.x * 16, n0 = blockIdx.y * 16;
  const int tx = threadIdx.x & 15, ty = threadIdx.x >> 4;
  t[ty][tx] = W[(size_t)(n0 + ty) * K + k0 + tx];
  __syncthreads();
  WT[(size_t)(k0 + ty) * N + n0 + tx] = t[tx][ty];
}

// ---------------------------------------------------------------------------
// GEMM1: C[M][128] = A[M][K-slice] . BT[K-slice][128] raw partials.
// r12/r17's proven kernel (64x128 tile, 128 thr, 8x8/thread, BK=16):
// 2-way split-K {0,400},{400,384}; part p -> C + p*coff. r19 confirmed the
// split's 3200-block queue depth is worth ~20us on GEMM1 (occupancy 35 vs
// 26%), more than the ~13us combine cost.
// ---------------------------------------------------------------------------
__global__ __launch_bounds__(128, 4) void gemm64bt2(
    const float* __restrict__ A, const float* __restrict__ BT,
    float* __restrict__ C, size_t coff) {
  constexpr int BM = 64, BK = 16, KS = kI;
  __shared__ float As[BK][68];
  __shared__ float Bs[BK][132];
  const int tid = threadIdx.x;
  const int tx = tid & 15;
  const int ty = tid >> 4;
  const int tile = blockIdx.x >> 1;
  const int half = blockIdx.x & 1;
  const int kbeg = half ? 400 : 0;
  const int nsteps = half ? 24 : 25;
  if (half) C += coff;
  const int row0 = tile * BM;

  const int ar0 = tid >> 2;        // 0..31
  const int ar1 = ar0 + 32;
  const int ac4 = (tid & 3) * 4;
  const int sbk = tid >> 5;        // 0..3
  const int sbn4 = (tid & 31) * 4; // 0..124

  const float* aptr = A + (size_t)(row0 + ar0) * KS + kbeg + ac4;
  const float* btptr = BT + (size_t)(kbeg + sbk) * 128 + sbn4;

  float acc[8][8];
#pragma unroll
  for (int i = 0; i < 8; ++i)
#pragma unroll
    for (int j = 0; j < 8; ++j) acc[i][j] = 0.0f;

  for (int s = 0; s < nsteps; ++s) {
    const int k0 = s * BK;
    __syncthreads();
    {
      const float4 va0 = *reinterpret_cast<const float4*>(aptr + k0);
      const float4 va1 =
          *reinterpret_cast<const float4*>(aptr + (size_t)32 * KS + k0);
      As[ac4 + 0][ar0] = va0.x; As[ac4 + 1][ar0] = va0.y;
      As[ac4 + 2][ar0] = va0.z; As[ac4 + 3][ar0] = va0.w;
      As[ac4 + 0][ar1] = va1.x; As[ac4 + 1][ar1] = va1.y;
      As[ac4 + 2][ar1] = va1.z; As[ac4 + 3][ar1] = va1.w;
#pragma unroll
      for (int l = 0; l < 4; ++l) {
        const float4 vb = *reinterpret_cast<const float4*>(
            btptr + (size_t)(k0 + l * 4) * 128);
        *reinterpret_cast<float4*>(&Bs[sbk + l * 4][sbn4]) = vb;
      }
    }
    __syncthreads();
#pragma unroll
    for (int kk = 0; kk < BK; ++kk) {
      float a[8], b[8];
      *reinterpret_cast<float4*>(&a[0]) =
          *reinterpret_cast<const float4*>(&As[kk][ty * 4]);
      *reinterpret_cast<float4*>(&a[4]) =
          *reinterpret_cast<const float4*>(&As[kk][32 + ty * 4]);
      *reinterpret_cast<float4*>(&b[0]) =
          *reinterpret_cast<const float4*>(&Bs[kk][tx * 4]);
      *reinterpret_cast<float4*>(&b[4]) =
          *reinterpret_cast<const float4*>(&Bs[kk][64 + tx * 4]);
#pragma unroll
      for (int i = 0; i < 8; ++i)
#pragma unroll
        for (int j = 0; j < 8; ++j) acc[i][j] = fmaf(a[i], b[j], acc[i][j]);
    }
  }

#pragma unroll
  for (int i = 0; i < 8; ++i) {
    const int m = (i < 4) ? (ty * 4 + i) : (32 + ty * 4 + (i - 4));
    const size_t r = (size_t)(row0 + m);
#pragma unroll
    for (int jh = 0; jh < 2; ++jh) {
      const int n = jh * 64 + tx * 4;
      float4 v;
      v.x = acc[i][jh * 4 + 0];
      v.y = acc[i][jh * 4 + 1];
      v.z = acc[i][jh * 4 + 2];
      v.w = acc[i][jh * 4 + 3];
      *reinterpret_cast<float4*>(&C[r * 128 + n]) = v;
    }
  }
}

// ---------------------------------------------------------------------------
// GEMM2: cur2[M][128] = s1_u8[M][128] . W2T[128][128] + b2. float(u8 in
// {0,1}) is exact -> bitwise-identical to the fp32 path. (r17 verbatim)
// ---------------------------------------------------------------------------
__global__ __launch_bounds__(128, 4) void gemm64u8(
    const unsigned char* __restrict__ A, const float* __restrict__ BT,
    const float* __restrict__ bias, float* __restrict__ C) {
  constexpr int BM = 64, BK = 16, KS = kH;
  __shared__ float As[BK][68];
  __shared__ float Bs[BK][132];
  const int tid = threadIdx.x;
  const int tx = tid & 15;
  const int ty = tid >> 4;
  const int row0 = blockIdx.x * BM;

  const int ar0 = tid >> 2;
  const int ar1 = ar0 + 32;
  const int ac4 = (tid & 3) * 4;
  const int sbk = tid >> 5;
  const int sbn4 = (tid & 31) * 4;

  const unsigned char* aptr = A + (size_t)(row0 + ar0) * KS + ac4;
  const float* btptr = BT + (size_t)sbk * 128 + sbn4;

  float acc[8][8];
#pragma unroll
  for (int i = 0; i < 8; ++i)
#pragma unroll
    for (int j = 0; j < 8; ++j) acc[i][j] = 0.0f;

  for (int s = 0; s < KS / BK; ++s) {
    const int k0 = s * BK;
    __syncthreads();
    {
      const uchar4 ua0 = *reinterpret_cast<const uchar4*>(aptr + k0);
      const uchar4 ua1 =
          *reinterpret_cast<const uchar4*>(aptr + (size_t)32 * KS + k0);
      As[ac4 + 0][ar0] = (float)ua0.x; As[ac4 + 1][ar0] = (float)ua0.y;
      As[ac4 + 2][ar0] = (float)ua0.z; As[ac4 + 3][ar0] = (float)ua0.w;
      As[ac4 + 0][ar1] = (float)ua1.x; As[ac4 + 1][ar1] = (float)ua1.y;
      As[ac4 + 2][ar1] = (float)ua1.z; As[ac4 + 3][ar1] = (float)ua1.w;
#pragma unroll
      for (int l = 0; l < 4; ++l) {
        const float4 vb = *reinterpret_cast<const float4*>(
            btptr + (size_t)(k0 + l * 4) * 128);
        *reinterpret_cast<float4*>(&Bs[sbk + l * 4][sbn4]) = vb;
      }
    }
    __syncthreads();
#pragma unroll
    for (int kk = 0; kk < BK; ++kk) {
      float a[8], b[8];
      *reinterpret_cast<float4*>(&a[0]) =
          *reinterpret_cast<const float4*>(&As[kk][ty * 4]);
      *reinterpret_cast<float4*>(&a[4]) =
          *reinterpret_cast<const float4*>(&As[kk][32 + ty * 4]);
      *reinterpret_cast<float4*>(&b[0]) =
          *reinterpret_cast<const float4*>(&Bs[kk][tx * 4]);
      *reinterpret_cast<float4*>(&b[4]) =
          *reinterpret_cast<const float4*>(&Bs[kk][64 + tx * 4]);
#pragma unroll
      for (int i = 0; i < 8; ++i)
#pragma unroll
        for (int j = 0; j < 8; ++j) acc[i][j] = fmaf(a[i], b[j], acc[i][j]);
    }
  }

#pragma unroll
  for (int i = 0; i < 8; ++i) {
    const int m = (i < 4) ? (ty * 4 + i) : (32 + ty * 4 + (i - 4));
    const size_t r = (size_t)(row0 + m);
#pragma unroll
    for (int jh = 0; jh < 2; ++jh) {
      const int n = jh * 64 + tx * 4;
      float4 v;
      v.x = acc[i][jh * 4 + 0] + bias[n + 0];
      v.y = acc[i][jh * 4 + 1] + bias[n + 1];
      v.z = acc[i][jh * 4 + 2] + bias[n + 2];
      v.w = acc[i][jh * 4 + 3] + bias[n + 3];
      *reinterpret_cast<float4*>(&C[r * 128 + n]) = v;
    }
  }
}

#define LIF_STEP(mm, ss, curexpr)                                      \
  {                                                                    \
    const float cur_ = (curexpr);                                      \
    mm = __fsub_rn(__fadd_rn(__fmul_rn(kBeta, mm), cur_), ss);         \
    ss = (mm > kThr) ? 1.0f : 0.0f;                                    \
  }

// ---------------------------------------------------------------------------
// Layer-1 LIF scan + combine: cur = (P0+P1)+b1; spikes -> S1 as u8 (exact).
// (r17 verbatim, absmax 0.0)
// ---------------------------------------------------------------------------
__global__ __launch_bounds__(128) void lif_scan13_u8(
    const float* __restrict__ P0, const float* __restrict__ P1,
    const float* __restrict__ b1, unsigned char* __restrict__ S1) {
  const int g = blockIdx.x * 128 + threadIdx.x;  // 0..32767
  const int b = g >> 6;
  const int h2 = (g & 63) * 2;
  const size_t base = (size_t)b * kT * 128 + h2;
  const float bb0 = b1[h2], bb1 = b1[h2 + 1];
#define LD0(t) (*reinterpret_cast<const float2*>(&P0[base + (size_t)(t)*128]))
#define LD1(t) (*reinterpret_cast<const float2*>(&P1[base + (size_t)(t)*128]))
  float2 cA0 = LD0(0), cA1 = LD1(0), cB0 = LD0(1), cB1 = LD1(1);
  float2 cC0 = LD0(2), cC1 = LD1(2), cD0 = LD0(3), cD1 = LD1(3);
  float m0 = 0.f, m1 = 0.f, s0 = 0.f, s1 = 0.f;
  for (int t = 0; t < kT; t += 2) {
    const int pa = (t + 4 < kT) ? t + 4 : kT - 1;
    const int pb = (t + 5 < kT) ? t + 5 : kT - 1;
    const float2 nA0 = LD0(pa), nA1 = LD1(pa);
    const float2 nB0 = LD0(pb), nB1 = LD1(pb);
    LIF_STEP(m0, s0, __fadd_rn(__fadd_rn(cA0.x, cA1.x), bb0));
    LIF_STEP(m1, s1, __fadd_rn(__fadd_rn(cA0.y, cA1.y), bb1));
    *reinterpret_cast<uchar2*>(&S1[base + (size_t)t * 128]) =
        make_uchar2((unsigned char)s0, (unsigned char)s1);
    LIF_STEP(m0, s0, __fadd_rn(__fadd_rn(cB0.x, cB1.x), bb0));
    LIF_STEP(m1, s1, __fadd_rn(__fadd_rn(cB0.y, cB1.y), bb1));
    *reinterpret_cast<uchar2*>(&S1[base + (size_t)(t + 1) * 128]) =
        make_uchar2((unsigned char)s0, (unsigned char)s1);
    cA0 = cC0; cA1 = cC1; cB0 = cD0; cB1 = cD1;
    cC0 = nA0; cC1 = nA1; cD0 = nB0; cD1 = nB1;
  }
#undef LD0
#undef LD1
}

// ---------------------------------------------------------------------------
// Layer-2 LIF scan: reads cur2 fp32, writes u8 spikes -> S2. (r17 verbatim)
// ---------------------------------------------------------------------------
__global__ __launch_bounds__(128) void lif_scan2_u8(
    const float* __restrict__ buf, unsigned char* __restrict__ S2) {
  const int g = blockIdx.x * 128 + threadIdx.x;  // 0..32767
  const int b = g >> 6;
  const int h2 = (g & 63) * 2;
  const size_t base = (size_t)b * kT * 128 + h2;
#define LD(t) (*reinterpret_cast<const float2*>(&buf[base + (size_t)(t)*128]))
  float2 cA = LD(0), cB = LD(1), cC = LD(2), cD = LD(3);
  float m0 = 0.f, m1 = 0.f, s0 = 0.f, s1 = 0.f;
  for (int t = 0; t < kT; t += 2) {
    const int pa = (t + 4 < kT) ? t + 4 : kT - 1;
    const int pb = (t + 5 < kT) ? t + 5 : kT - 1;
    const float2 nA = LD(pa), nB = LD(pb);
    LIF_STEP(m0, s0, cA.x);
    LIF_STEP(m1, s1, cA.y);
    *reinterpret_cast<uchar2*>(&S2[base + (size_t)t * 128]) =
        make_uchar2((unsigned char)s0, (unsigned char)s1);
    LIF_STEP(m0, s0, cB.x);
    LIF_STEP(m1, s1, cB.y);
    *reinterpret_cast<uchar2*>(&S2[base + (size_t)(t + 1) * 128]) =
        make_uchar2((unsigned char)s0, (unsigned char)s1);
    cA = cC; cB = cD; cC = nA; cD = nB;
  }
#undef LD
}

// ---------------------------------------------------------------------------
// GEMM3: cur3[M][10] = s2_u8[M][128] . W3[10][128]^T + b3. (r17 verbatim)
// ---------------------------------------------------------------------------
__global__ __launch_bounds__(320) void gemm3_u8(
    const unsigned char* __restrict__ A, const float* __restrict__ W3,
    const float* __restrict__ b3, float* __restrict__ C) {
  __shared__ float Ss[64][132];
  __shared__ float Ws[10][132];
  __shared__ float bs[10];
  const int tid = threadIdx.x;
  const size_t row0 = (size_t)blockIdx.x * 64;

  {
    const int r = tid >> 5;
    const int c4 = (tid & 31) * 4;
    const float4 v = *reinterpret_cast<const float4*>(&W3[r * 128 + c4]);
    Ws[r][c4 + 0] = v.x;
    Ws[r][c4 + 1] = v.y;
    Ws[r][c4 + 2] = v.z;
    Ws[r][c4 + 3] = v.w;
    if (tid < 10) bs[tid] = b3[tid];
  }
  for (int fi = tid; fi < 2048; fi += 320) {
    const int r = fi >> 5;
    const int c4 = (fi & 31) * 4;
    const uchar4 v =
        *reinterpret_cast<const uchar4*>(&A[(row0 + r) * 128 + c4]);
    Ss[r][c4 + 0] = (float)v.x;
    Ss[r][c4 + 1] = (float)v.y;
    Ss[r][c4 + 2] = (float)v.z;
    Ss[r][c4 + 3] = (float)v.w;
  }
  __syncthreads();

#pragma unroll
  for (int l = 0; l < 2; ++l) {
    const int idx = tid + l * 320;
    const int r = idx / 10;
    const int o = idx - r * 10;
    float acc = bs[o];
#pragma unroll
    for (int k = 0; k < 128; k += 4) {
      const float4 a = *reinterpret_cast<const float4*>(&Ss[r][k]);
      const float4 w = *reinterpret_cast<const float4*>(&Ws[o][k]);
      acc = fmaf(a.x, w.x, acc);
      acc = fmaf(a.y, w.y, acc);
      acc = fmaf(a.z, w.z, acc);
      acc = fmaf(a.w, w.w, acc);
    }
    C[(row0 + r) * 10 + o] = acc;
  }
}

// ---------------------------------------------------------------------------
// Output LIF scan -> out[t][b][o]. (unchanged, proven)
// ---------------------------------------------------------------------------
__global__ __launch_bounds__(256) void lif_scan_out(
    const float* __restrict__ cur3, float* __restrict__ out) {
  const int g = blockIdx.x * 256 + threadIdx.x;  // 0..5119
  if (g >= kB * kO) return;
  const int b = g / kO;
  const int o = g - b * kO;
  float m = 0.0f, s = 0.0f;
#pragma unroll 4
  for (int t = 0; t < kT; ++t) {
    const float c = cur3[((size_t)b * kT + t) * kO + o];
    m = __fsub_rn(__fadd_rn(__fmul_rn(kBeta, m), c), s);
    s = (m > kThr) ? 1.0f : 0.0f;
    out[(size_t)t * (kB * kO) + g] = s;
  }
}

extern "C" void kernel_launch(void* const* d_in, const int* in_sizes, int n_in,
                              void* d_out, int out_size, void* d_ws,
                              size_t ws_size, hipStream_t stream) {
  (void)in_sizes;
  (void)n_in;
  (void)out_size;
  (void)ws_size;
  const float* x = (const float*)d_in[0];    // [B,T,784]
  const float* W1 = (const float*)d_in[1];   // [128,784]
  const float* b1 = (const float*)d_in[2];   // [128]
  const float* W2 = (const float*)d_in[3];   // [128,128]
  const float* b2 = (const float*)d_in[4];   // [128]
  const float* W3 = (const float*)d_in[5];   // [10,128]
  const float* b3 = (const float*)d_in[6];   // [10]
  float* out = (float*)d_out;                // [T,B,10] = 4.1 MB

  const size_t bufElems = (size_t)kM * kH;   // 13.1M elems
  float* P0 = (float*)d_ws;                  // partial0 -> cur2
  float* P1 = P0 + bufElems;                 // partial1 -> cur3
  unsigned char* S1 = (unsigned char*)(P1 + bufElems);  // s1 u8, 13.1 MB
  unsigned char* S2 = S1 + bufElems;                    // s2 u8, 13.1 MB

  // W1T + W2T (467 KB) stashed at head of d_out; overwritten by the final
  // lif_scan_out (proven r10-r17 pattern).
  float* W1T = out;
  float* W2T = W1T + (size_t)kI * kH;

  transposeW<<<dim3(kI / 16, kH / 16), 256, 0, stream>>>(W1, W1T, kH, kI);
  transposeW<<<dim3(kH / 16, kH / 16), 256, 0, stream>>>(W2, W2T, kH, kH);

  // Layer 1: 2-way split-K GEMM (r12 config), partials P0,P1; scan -> S1 u8.
  gemm64bt2<<<2 * (kM / 64), 128, 0, stream>>>(x, W1T, P0, bufElems);
  lif_scan13_u8<<<256, 128, 0, stream>>>(P0, P1, b1, S1);
  // Layer 2: full-K u8-A GEMM, bias fused; cur2 -> P0; scan -> S2 u8.
  gemm64u8<<<kM / 64, 128, 0, stream>>>(S1, W2T, b2, P0);
  lif_scan2_u8<<<256, 128, 0, stream>>>(P0, S2);
  // Layer 3: cur3 -> P1; final scan -> out.
  gemm3_u8<<<kM / 64, 320, 0, stream>>>(S2, W3, b3, P1);
  lif_scan_out<<<(kB * kO + 255) / 256, 256, 0, stream>>>(P1, out);
}